// Round 5
// baseline (656.423 us; speedup 1.0000x reference)
//
#include <hip/hip_runtime.h>
#include <hip/hip_bf16.h>

// LSTM: B=16384, T=200, IN=9, H=64, OUT=3, 2 layers + linear head.
// Round 5: wave-specialized layer pipeline.
//   512 threads = 8 waves. Waves 0-3: layer1 of step s. Waves 4-7: layer2 of
//   step s-1 (layer1 never depends on layer2 => 1-step software pipeline).
//   Each wave owns 4 gate-tiles of ONE layer: 12-16 frags = 48-64 VGPR
//   (shared fr[16] array, branch-dependent content), 4 cell-updates/lane
//   (halved transcendental load vs R4).
//   h1/h2 double-buffered in LDS; reads from parity (s-1), writes parity s
//   => ONE __syncthreads per step.
//   x: direct global prefetch into regs (window LDS deleted).
// Fragment layouts (gfx950 16x16x32, verified R2-R4):
//   A: lane l holds A[m=l&15][k=4*(l>>4)+(j&3)+16*(j>>2)]
//   B: lane l holds B[k=...][n=l&15]
//   C/D: col=l&15, row=(l>>4)*4+reg
// LDS h-state k-PERMUTED (R3): k=c*32+4q+s -> pos=c*32+8q+s ; +16 -> +4
// Weights pre-scaled (R4): i,f,o rows x(-log2e); g rows x(+2*log2e).

#define B_TOT   16384
#define T_STEPS 200
#define IN_DIM  9
#define HDIM    64

#define PK1_OFF 0         // [3][16][64][8] = 24576 f16
#define PK2_OFF 24576     // [4][16][64][8] = 32768 f16
#define BSUM_HALF_OFF 57344   // then 512 f32 (b1[256], b2[256])
#define PACK_W_TOT 57344
#define PACK_TOT (PACK_W_TOT + 512)

#define L2E      1.44269504089f
#define NEG2L2E -2.88539008178f

typedef _Float16 half8 __attribute__((ext_vector_type(8)));
typedef float    f32x4 __attribute__((ext_vector_type(4)));
typedef float    f4u   __attribute__((ext_vector_type(4), aligned(4)));  // 4B-aligned float4

__device__ __forceinline__ float sig_y(float y) {           // y pre-scaled
    return __builtin_amdgcn_rcpf(1.0f + __builtin_amdgcn_exp2f(y));
}

// ---------------- prep: repack weights (B-frag layout, act-scales folded) ----
__global__ void pack_kernel(const float* __restrict__ Wih1, const float* __restrict__ Whh1,
                            const float* __restrict__ bih1, const float* __restrict__ bhh1,
                            const float* __restrict__ Wih2, const float* __restrict__ Whh2,
                            const float* __restrict__ bih2, const float* __restrict__ bhh2,
                            float* __restrict__ ws) {
    int e = blockIdx.x * 256 + threadIdx.x;
    if (e >= PACK_TOT) return;
    _Float16* wh = (_Float16*)ws;
    float* bptr = (float*)(wh + BSUM_HALF_OFF);
    auto gscale = [](int q) -> float {
        int gt = q >> 6;
        return (gt == 2) ? (2.0f * L2E) : -L2E;
    };
    if (e < PK2_OFF) {
        int j = e & 7, lane = (e >> 3) & 63, nt = (e >> 9) & 15, c = e >> 13;
        int k = c * 32 + 4 * (lane >> 4) + (j & 3) + 16 * (j >> 2);
        int q = nt * 16 + (lane & 15);
        float v = 0.0f;
        if (k < 64)      v = Whh1[q * 64 + k];
        else if (k < 73) v = Wih1[q * 9 + (k - 64)];
        wh[e] = (_Float16)(v * gscale(q));
    } else if (e < PACK_W_TOT) {
        int e2 = e - PK2_OFF;
        int j = e2 & 7, lane = (e2 >> 3) & 63, nt = (e2 >> 9) & 15, c = e2 >> 13;
        int k = c * 32 + 4 * (lane >> 4) + (j & 3) + 16 * (j >> 2);
        int q = nt * 16 + (lane & 15);
        float v = (k < 64) ? Wih2[q * 64 + k] : Whh2[q * 64 + (k - 64)];
        wh[e] = (_Float16)(v * gscale(q));
    } else if (e < PACK_W_TOT + 256) {
        int q = e - PACK_W_TOT;
        bptr[q] = (bih1[q] + bhh1[q]) * gscale(q);
    } else {
        int q = e - PACK_W_TOT - 256;
        bptr[256 + q] = (bih2[q] + bhh2[q]) * gscale(q);
    }
}

// ---------------- main: layer-pipelined LSTM ----------------
__global__ __launch_bounds__(512, 2) void lstm_pipe(
    const float* __restrict__ x,
    const float* __restrict__ ws_f,
    const float* __restrict__ Wout,
    const float* __restrict__ bout,
    float* __restrict__ out)
{
    const int tid  = threadIdx.x;
    const int lane = tid & 63;
    const int w    = __builtin_amdgcn_readfirstlane(tid >> 6);   // 0..7
    const int l15  = lane & 15;
    const int l4   = lane >> 4;
    const int cg   = w & 3;                 // cell-group (both roles)
    const bool isL1 = (w < 4);

    const _Float16* wh  = (const _Float16*)ws_f;
    const _Float16* pk1 = wh + PK1_OFF;
    const _Float16* pk2 = wh + PK2_OFF;
    const float* bsum   = (const float*)(wh + BSUM_HALF_OFF);

    __shared__ _Float16 h1s[2][16][72];
    __shared__ _Float16 h2s[2][16][72];

    for (int i = tid; i < 2 * 16 * 72; i += 512) {
        (&h1s[0][0][0])[i] = (_Float16)0.0f;
        (&h2s[0][0][0])[i] = (_Float16)0.0f;
    }

    const int bbase = blockIdx.x * 16;
    const float* xb = x + (long)(bbase + l15) * (T_STEPS * IN_DIM);

    // ---- weight fragments: 16 x half8 = 64 VGPR, branch-dependent content
    half8 fr[16];
    if (isL1) {
        #pragma unroll
        for (int c = 0; c < 3; ++c)
            #pragma unroll
            for (int g = 0; g < 4; ++g)
                fr[c * 4 + g] = *(const half8*)(pk1 + (((c * 16) + (cg + 4 * g)) * 64 + lane) * 8);
        #pragma unroll
        for (int g = 0; g < 4; ++g) {
            half8 z;
            #pragma unroll
            for (int j = 0; j < 8; ++j) z[j] = (_Float16)0.0f;
            fr[12 + g] = z;
        }
    } else {
        #pragma unroll
        for (int c = 0; c < 4; ++c)
            #pragma unroll
            for (int g = 0; g < 4; ++g)
                fr[c * 4 + g] = *(const half8*)(pk2 + (((c * 16) + (cg + 4 * g)) * 64 + lane) * 8);
    }

    float bias[4];
    #pragma unroll
    for (int g = 0; g < 4; ++g)
        bias[g] = isL1 ? bsum[(cg + 4 * g) * 16 + l15]
                       : bsum[256 + (cg + 4 * g) * 16 + l15];

    // write perm-position of this thread's cell j = cg*16 + l15
    const int hpos = ((cg >> 1) << 5) + 8 * (l15 >> 2) + (l15 & 3) + ((cg & 1) << 2);

    float cst[4] = {0.f, 0.f, 0.f, 0.f};   // c1 (L1 waves) or c2 (L2 waves)

    // x prefetch regs (L1 waves): step-0 values
    f4u  cx  = {0.f, 0.f, 0.f, 0.f};
    float cx8 = 0.0f;
    if (isL1) {
        if (l4 < 2)       cx  = *(const f4u*)(xb + 4 * l4);
        else if (l4 == 2) cx8 = xb[8];
    }

    // swapped LDS buffer pointers: reads from parity (s-1), writes parity s
    _Float16* h1r = &h1s[1][0][0];
    _Float16* h1w = &h1s[0][0][0];
    _Float16* h2r = &h2s[1][0][0];
    _Float16* h2w = &h2s[0][0][0];

    __syncthreads();   // zero-init visible

    for (int s = 0; s <= T_STEPS; ++s) {
        // pin weight frags: loop-carried in VGPRs, no remat-by-reload
        asm volatile("" :
            "+v"(fr[0]),  "+v"(fr[1]),  "+v"(fr[2]),  "+v"(fr[3]),
            "+v"(fr[4]),  "+v"(fr[5]),  "+v"(fr[6]),  "+v"(fr[7]),
            "+v"(fr[8]),  "+v"(fr[9]),  "+v"(fr[10]), "+v"(fr[11]),
            "+v"(fr[12]), "+v"(fr[13]), "+v"(fr[14]), "+v"(fr[15]));

        if (isL1) {
            if (s < T_STEPS) {
                // build x A-frag from prefetched regs
                float e0 = (l4 == 2) ? cx8 : cx[0];
                half8 ax;
                ax[0] = (_Float16)e0;    ax[1] = (_Float16)cx[1];
                ax[2] = (_Float16)cx[2]; ax[3] = (_Float16)cx[3];
                ax[4] = ax[5] = ax[6] = ax[7] = (_Float16)0.0f;

                // prefetch x(s+1)
                if (s + 1 < T_STEPS) {
                    const float* xp = xb + (s + 1) * IN_DIM;
                    if (l4 < 2)       cx  = *(const f4u*)(xp + 4 * l4);
                    else if (l4 == 2) cx8 = xp[8];
                }

                half8 a1c0 = *(const half8*)(h1r + l15 * 72 +  0 + 8 * l4);
                half8 a1c1 = *(const half8*)(h1r + l15 * 72 + 32 + 8 * l4);

                f32x4 C[4];
                #pragma unroll
                for (int g = 0; g < 4; ++g) C[g] = (f32x4){bias[g], bias[g], bias[g], bias[g]};
                #pragma unroll
                for (int g = 0; g < 4; ++g)
                    C[g] = __builtin_amdgcn_mfma_f32_16x16x32_f16(a1c0, fr[0 + g], C[g], 0, 0, 0);
                #pragma unroll
                for (int g = 0; g < 4; ++g)
                    C[g] = __builtin_amdgcn_mfma_f32_16x16x32_f16(a1c1, fr[4 + g], C[g], 0, 0, 0);
                #pragma unroll
                for (int g = 0; g < 4; ++g)
                    C[g] = __builtin_amdgcn_mfma_f32_16x16x32_f16(ax,   fr[8 + g], C[g], 0, 0, 0);

                #pragma unroll
                for (int r = 0; r < 4; ++r) {
                    float ig = sig_y(C[0][r]);
                    float fg = sig_y(C[1][r]);
                    float gg = __builtin_fmaf(-2.0f, sig_y(C[2][r]), 1.0f);
                    float og = sig_y(C[3][r]);
                    float cc = __builtin_fmaf(fg, cst[r], ig * gg);
                    cst[r] = cc;
                    float th = __builtin_fmaf(2.0f, sig_y(cc * NEG2L2E), -1.0f);
                    h1w[(4 * l4 + r) * 72 + hpos] = (_Float16)(og * th);
                }
            }
        } else {
            if (s > 0) {
                half8 a20  = *(const half8*)(h1r + l15 * 72 +  0 + 8 * l4);
                half8 a21  = *(const half8*)(h1r + l15 * 72 + 32 + 8 * l4);
                half8 a2h0 = *(const half8*)(h2r + l15 * 72 +  0 + 8 * l4);
                half8 a2h1 = *(const half8*)(h2r + l15 * 72 + 32 + 8 * l4);

                f32x4 C[4];
                #pragma unroll
                for (int g = 0; g < 4; ++g) C[g] = (f32x4){bias[g], bias[g], bias[g], bias[g]};
                #pragma unroll
                for (int g = 0; g < 4; ++g)
                    C[g] = __builtin_amdgcn_mfma_f32_16x16x32_f16(a20,  fr[0 + g],  C[g], 0, 0, 0);
                #pragma unroll
                for (int g = 0; g < 4; ++g)
                    C[g] = __builtin_amdgcn_mfma_f32_16x16x32_f16(a21,  fr[4 + g],  C[g], 0, 0, 0);
                #pragma unroll
                for (int g = 0; g < 4; ++g)
                    C[g] = __builtin_amdgcn_mfma_f32_16x16x32_f16(a2h0, fr[8 + g],  C[g], 0, 0, 0);
                #pragma unroll
                for (int g = 0; g < 4; ++g)
                    C[g] = __builtin_amdgcn_mfma_f32_16x16x32_f16(a2h1, fr[12 + g], C[g], 0, 0, 0);

                #pragma unroll
                for (int r = 0; r < 4; ++r) {
                    float ig = sig_y(C[0][r]);
                    float fg = sig_y(C[1][r]);
                    float gg = __builtin_fmaf(-2.0f, sig_y(C[2][r]), 1.0f);
                    float og = sig_y(C[3][r]);
                    float cc = __builtin_fmaf(fg, cst[r], ig * gg);
                    cst[r] = cc;
                    float th = __builtin_fmaf(2.0f, sig_y(cc * NEG2L2E), -1.0f);
                    h2w[(4 * l4 + r) * 72 + hpos] = (_Float16)(og * th);
                }
            }
        }
        __syncthreads();   // h1(s), h2(s-1) visible; parity flip
        _Float16* t;
        t = h1r; h1r = h1w; h1w = t;
        t = h2r; h2r = h2w; h2w = t;
    }

    // ---- output head: h2(199) is in h2s[0] (s=200 wrote parity 0)
    if (tid < 48) {
        int bl = tid / 3, o = tid - bl * 3;
        float acc = bout[o];
        #pragma unroll 8
        for (int pos = 0; pos < HDIM; ++pos) {
            int sub = pos & 31;
            int j = (pos >> 5) * 32 + (((sub >> 2) & 1) << 4) + ((sub >> 3) << 2) + (sub & 3);
            acc = __builtin_fmaf(Wout[o * 64 + j], (float)h2s[0][bl][pos], acc);
        }
        out[(bbase + bl) * 3 + o] = acc;
    }
}

extern "C" void kernel_launch(void* const* d_in, const int* in_sizes, int n_in,
                              void* d_out, int out_size, void* d_ws, size_t ws_size,
                              hipStream_t stream) {
    const float* x     = (const float*)d_in[0];
    const float* Wih1  = (const float*)d_in[1];
    const float* Whh1  = (const float*)d_in[2];
    const float* bih1  = (const float*)d_in[3];
    const float* bhh1  = (const float*)d_in[4];
    const float* Wih2  = (const float*)d_in[5];
    const float* Whh2  = (const float*)d_in[6];
    const float* bih2  = (const float*)d_in[7];
    const float* bhh2  = (const float*)d_in[8];
    const float* Wout  = (const float*)d_in[9];
    const float* bout  = (const float*)d_in[10];
    float* ws  = (float*)d_ws;
    float* out = (float*)d_out;

    pack_kernel<<<(PACK_TOT + 255) / 256, 256, 0, stream>>>(
        Wih1, Whh1, bih1, bhh1, Wih2, Whh2, bih2, bhh2, ws);

    lstm_pipe<<<B_TOT / 16, 512, 0, stream>>>(x, ws, Wout, bout, out);
}